// Round 11
// baseline (161.624 us; speedup 1.0000x reference)
//
#include <hip/hip_runtime.h>
#include <cstdint>
#include <cstddef>

#define BATCH 256
#define NN 400
#define HH 256
#define TDIM 128
#define HALFD 64
#define OUTD 800
#define BITW 16     // u32 words per bitmap row in global (13 used)
#define BMW 13
#define W2PAD 264   // W2T row stride (shorts)
#define Y2S 416     // y2 quarter LDS row stride (shorts)

using short8  = __attribute__((ext_vector_type(8))) short;
using short4v = __attribute__((ext_vector_type(4))) short;
using f32x4   = __attribute__((ext_vector_type(4))) float;

__device__ __forceinline__ short f2bf_trunc(float x) {
  union { float f; unsigned int u; } c; c.f = x; return (short)(c.u >> 16);
}
__device__ __forceinline__ short f2bf_rne(float x) {
  union { float f; unsigned int u; } c; c.f = x;
  unsigned int r = c.u + 0x7FFFu + ((c.u >> 16) & 1u);
  return (short)(r >> 16);
}

// ---- K1: adj -> bitmap [256][400][16 u32] (binary + self loop), dis, dd.
__global__ __launch_bounds__(256) void k_prep(const float* __restrict__ adj,
    unsigned int* __restrict__ bits, float* __restrict__ dis,
    float* __restrict__ dd) {
  int bg = blockIdx.x;
  int rbase = blockIdx.y * 16;
  int wv = threadIdx.x >> 6, lane = threadIdx.x & 63;
#pragma unroll
  for (int rr = 0; rr < 4; ++rr) {
    int i = rbase + wv * 4 + rr;
    const float* arow = adj + ((size_t)bg * NN + i) * NN;
    unsigned int b8 = 0; int c = 0;
    if (lane < 50) {
      float4 v0 = *(const float4*)(arow + 8 * lane);
      float4 v1 = *(const float4*)(arow + 8 * lane + 4);
      b8 = (v0.x != 0.f ? 1u : 0u) | (v0.y != 0.f ? 2u : 0u) |
           (v0.z != 0.f ? 4u : 0u) | (v0.w != 0.f ? 8u : 0u) |
           (v1.x != 0.f ? 16u : 0u) | (v1.y != 0.f ? 32u : 0u) |
           (v1.z != 0.f ? 64u : 0u) | (v1.w != 0.f ? 128u : 0u);
      c = __popc(b8);
      if ((i >> 3) == lane) b8 |= 1u << (i & 7);  // self loop
    }
    int cs = c;
#pragma unroll
    for (int s = 32; s; s >>= 1) cs += __shfl_xor(cs, s);
    unsigned int p0 = (unsigned int)__shfl((int)b8, 4 * lane);
    unsigned int p1 = (unsigned int)__shfl((int)b8, 4 * lane + 1);
    unsigned int p2 = (unsigned int)__shfl((int)b8, 4 * lane + 2);
    unsigned int p3 = (unsigned int)__shfl((int)b8, 4 * lane + 3);
    if (lane < BITW)
      bits[((size_t)bg * NN + i) * BITW + lane] =
          (lane < BMW) ? (p0 | (p1 << 8) | (p2 << 16) | (p3 << 24)) : 0u;
    if (lane == 0) {
      float d = rsqrtf((float)cs + 1.f);
      dis[bg * NN + i] = d;
      dd[bg * NN + i] = d * (float)cs;
    }
  }
}

// ---- K2: tproj[b,h] = temb(times[b]) @ W1[1:,:]
__global__ __launch_bounds__(256) void k_temb(
    const float* __restrict__ times, const float* __restrict__ W1,
    float* __restrict__ tproj) {
  int b = blockIdx.x, t = threadIdx.x;
  __shared__ float te[TDIM];
  if (t < HALFD) {
    float f = expf(-9.210340371976184f * (float)t / (float)(HALFD - 1));
    float arg = times[b] * f;
    te[t] = sinf(arg);
    te[t + HALFD] = cosf(arg);
  }
  __syncthreads();
  float acc = 0.f;
#pragma unroll 8
  for (int k = 0; k < TDIM; ++k) acc += te[k] * W1[(1 + k) * HH + t];
  tproj[b * HH + t] = acc;
}

// ---- K3: W2 -> bf16 transposed padded [256 n][264 k]
__global__ __launch_bounds__(256) void k_w2t(const float* __restrict__ W2,
                                             short* __restrict__ W2Tg) {
  int n = blockIdx.x, k = threadIdx.x;
  W2Tg[n * W2PAD + k] = f2bf_rne(W2[k * HH + n]);
}

// ---- K4: pp = dis_i*(As@dd), qq = dis_i*(As@dis) via bitmap ctz-walk.
__global__ __launch_bounds__(512) void k_pq(const unsigned int* __restrict__ bits,
    const float* __restrict__ dis, const float* __restrict__ dd,
    float* __restrict__ pp, float* __restrict__ qq) {
  int bg = blockIdx.x, t = threadIdx.x;
  __shared__ float sd[NN], su[NN];
  for (int j = t; j < NN; j += 512) { sd[j] = dis[bg * NN + j]; su[j] = dd[bg * NN + j]; }
  __syncthreads();
  if (t >= NN) return;
  const uint4* bp = (const uint4*)(bits + ((size_t)bg * NN + t) * BITW);
  uint4 qa = bp[0], qb = bp[1], qc = bp[2];
  unsigned int wr[13] = {qa.x, qa.y, qa.z, qa.w, qb.x, qb.y, qb.z, qb.w,
                         qc.x, qc.y, qc.z, qc.w, ((const unsigned int*)bp)[12]};
  float ps = 0.f, qs = 0.f;
#pragma unroll
  for (int w = 0; w < BMW; ++w) {
    unsigned int u = wr[w];
    int base = w * 32;
    while (u) {
      int j = base + __builtin_ctz(u);
      u &= u - 1;
      ps += su[j]; qs += sd[j];
    }
  }
  float d = sd[t];
  pp[bg * NN + t] = d * ps;
  qq[bg * NN + t] = d * qs;
}

// ---- K5: fused per-(graph, n-quarter): GEMM1(y2 quarter in LDS) ->
//      AGG (register-expanded bitmap A-frags, barrier-free K-loop) ->
//      relu -> pool. 512 thr, 8 waves, 3 barriers total.
__global__ __launch_bounds__(512, 2) void k_fused(
    const unsigned int* __restrict__ bits, const float* __restrict__ disg,
    const float* __restrict__ ppg, const float* __restrict__ qqg,
    const short* __restrict__ W2Tg, const float* __restrict__ W1,
    const float* __restrict__ b1, const float* __restrict__ tproj,
    const float* __restrict__ b2, float* __restrict__ pooled) {
  extern __shared__ char smem[];
  short* w2tq        = (short*)smem;                    // 64*264*2 = 33792
  short* y2q         = (short*)(smem + 33792);          // 64*416*2 = 53248 -> 87040
  unsigned int* bmpL = (unsigned int*)(smem + 87040);   // 400*13*4 = 20800 -> 107840
  float* sd          = (float*)(smem + 107840);         // 1600 -> 109440
  float* ppL         = (float*)(smem + 109440);         // 1600 -> 111040
  float* qqL         = (float*)(smem + 111040);         // 1600 -> 112640
  float* pool        = (float*)(smem + 112640);         // 8*64*4 = 2048 -> 114688

  int t = threadIdx.x;
  int wv = t >> 6, lane = t & 63, l15 = lane & 15, l4 = lane >> 4;
  int bg = blockIdx.x, q = blockIdx.y;

  // ---- stage: W2T quarter, bitmap, dis/pp/qq, zero y2q pad (m=400..415)
#pragma unroll
  for (int i = 0; i < 5; ++i) {
    int idx = i * 512 + t;
    if (idx < 2112) {  // 64 rows * 33 short8 chunks
      int n = idx / 33, c = idx % 33;
      *(short8*)(w2tq + n * W2PAD + c * 8) =
          *(const short8*)(W2Tg + (size_t)(q * 64 + n) * W2PAD + c * 8);
    }
  }
  if (t < NN) {
    const uint4* bp = (const uint4*)(bits + ((size_t)bg * NN + t) * BITW);
    uint4 qa = bp[0], qb = bp[1], qc = bp[2];
    bmpL[t * BMW + 0] = qa.x;  bmpL[t * BMW + 1] = qa.y;
    bmpL[t * BMW + 2] = qa.z;  bmpL[t * BMW + 3] = qa.w;
    bmpL[t * BMW + 4] = qb.x;  bmpL[t * BMW + 5] = qb.y;
    bmpL[t * BMW + 6] = qb.z;  bmpL[t * BMW + 7] = qb.w;
    bmpL[t * BMW + 8] = qc.x;  bmpL[t * BMW + 9] = qc.y;
    bmpL[t * BMW + 10] = qc.z; bmpL[t * BMW + 11] = qc.w;
    bmpL[t * BMW + 12] = ((const unsigned int*)bp)[12];
    sd[t] = disg[bg * NN + t];
    ppL[t] = ppg[bg * NN + t];
    qqL[t] = qqg[bg * NN + t];
  }
  if (t < 128) {  // zero y2q pad cols m=400..415 for all 64 n-rows
    int n = t >> 1, c = t & 1;
    short8 z = {};
    *(short8*)(y2q + n * Y2S + 400 + c * 8) = z;
  }
  __syncthreads();

  // ---- GEMM1: y2q[n][m] = dis_m * (g1 @ W2)[m][q*64+n]; k0 outer, mt inner
  const float* tpr = tproj + bg * HH;
  float pv[4], qv[4];
#pragma unroll
  for (int mi = 0; mi < 4; ++mi) {
    int mt = wv + mi * 8;
    int arow = mt * 16 + l15;
    pv[mi] = (mt < 25) ? ppL[arow] : 0.f;
    qv[mi] = (mt < 25) ? qqL[arow] : 0.f;
  }
  f32x4 acc[4][4];
#pragma unroll
  for (int mi = 0; mi < 4; ++mi)
#pragma unroll
    for (int f = 0; f < 4; ++f) acc[mi][f] = (f32x4){0.f, 0.f, 0.f, 0.f};

#pragma unroll
  for (int k0 = 0; k0 < 8; ++k0) {
    int kk = k0 * 32 + l4 * 8;
    float4 w1a = *(const float4*)(W1 + kk), w1b = *(const float4*)(W1 + kk + 4);
    float4 b1a = *(const float4*)(b1 + kk), b1b = *(const float4*)(b1 + kk + 4);
    float4 tpa = *(const float4*)(tpr + kk), tpb = *(const float4*)(tpr + kk + 4);
    short8 bf[4];
#pragma unroll
    for (int f = 0; f < 4; ++f)
      bf[f] = *(const short8*)(w2tq + (f * 16 + l15) * W2PAD + kk);
#pragma unroll
    for (int mi = 0; mi < 4; ++mi) {
      if (wv + mi * 8 < 25) {
        float ppv = pv[mi], qqv = qv[mi];
        short8 af;
        af[0] = f2bf_trunc(fmaxf(ppv * w1a.x + qqv * tpa.x + b1a.x, 0.f));
        af[1] = f2bf_trunc(fmaxf(ppv * w1a.y + qqv * tpa.y + b1a.y, 0.f));
        af[2] = f2bf_trunc(fmaxf(ppv * w1a.z + qqv * tpa.z + b1a.z, 0.f));
        af[3] = f2bf_trunc(fmaxf(ppv * w1a.w + qqv * tpa.w + b1a.w, 0.f));
        af[4] = f2bf_trunc(fmaxf(ppv * w1b.x + qqv * tpb.x + b1b.x, 0.f));
        af[5] = f2bf_trunc(fmaxf(ppv * w1b.y + qqv * tpb.y + b1b.y, 0.f));
        af[6] = f2bf_trunc(fmaxf(ppv * w1b.z + qqv * tpb.z + b1b.z, 0.f));
        af[7] = f2bf_trunc(fmaxf(ppv * w1b.w + qqv * tpb.w + b1b.w, 0.f));
#pragma unroll
        for (int f = 0; f < 4; ++f)
          acc[mi][f] = __builtin_amdgcn_mfma_f32_16x16x32_bf16(af, bf[f], acc[mi][f], 0, 0, 0);
      }
    }
  }
  // write y2q (transposed, dis-scaled): n = f*16+l15, m = mt*16 + l4*4 + r
#pragma unroll
  for (int mi = 0; mi < 4; ++mi) {
    int mt = wv + mi * 8;
    if (mt < 25) {
      float4 d4 = *(const float4*)(sd + mt * 16 + l4 * 4);
#pragma unroll
      for (int f = 0; f < 4; ++f) {
        short4v pk;
        pk[0] = f2bf_trunc(d4.x * acc[mi][f][0]);
        pk[1] = f2bf_trunc(d4.y * acc[mi][f][1]);
        pk[2] = f2bf_trunc(d4.z * acc[mi][f][2]);
        pk[3] = f2bf_trunc(d4.w * acc[mi][f][3]);
        *(short4v*)(y2q + (f * 16 + l15) * Y2S + mt * 16 + l4 * 4) = pk;
      }
    }
  }
  __syncthreads();

  // ---- AGG: C[m][n] = sum_k As[m][k]*y2q[n][k]; A-frags expanded in REGISTERS
  //      from LDS bitmap (broadcast b32 read). No LDS writes -> no barriers.
  f32x4 acc2[4][4];
#pragma unroll
  for (int mi = 0; mi < 4; ++mi)
#pragma unroll
    for (int f = 0; f < 4; ++f) acc2[mi][f] = (f32x4){0.f, 0.f, 0.f, 0.f};

#pragma unroll
  for (int ks = 0; ks < 13; ++ks) {
    short8 bfv[4];
#pragma unroll
    for (int f = 0; f < 4; ++f)
      bfv[f] = *(const short8*)(y2q + (f * 16 + l15) * Y2S + ks * 32 + l4 * 8);
#pragma unroll
    for (int mi = 0; mi < 4; ++mi) {
      int mt = wv + mi * 8;
      if (mt < 25) {
        unsigned int wd = bmpL[(mt * 16 + l15) * BMW + ks];
        unsigned int byt = (wd >> (l4 * 8)) & 0xFFu;
        short8 af;
#pragma unroll
        for (int e = 0; e < 8; ++e)
          af[e] = (short)(((byt >> e) & 1u) * 0x3F80u);
#pragma unroll
        for (int f = 0; f < 4; ++f)
          acc2[mi][f] = __builtin_amdgcn_mfma_f32_16x16x32_bf16(af, bfv[f], acc2[mi][f], 0, 0, 0);
      }
    }
  }

  // ---- epilogue: s(n) = sum_m relu(dis_m * C[m][n] + b2[n]); pool across waves
#pragma unroll
  for (int f = 0; f < 4; ++f) {
    float b2v = b2[q * 64 + f * 16 + l15];
    float s = 0.f;
#pragma unroll
    for (int mi = 0; mi < 4; ++mi) {
      int mt = wv + mi * 8;
      if (mt < 25) {
        float4 d4 = *(const float4*)(sd + mt * 16 + l4 * 4);
        s += fmaxf(d4.x * acc2[mi][f][0] + b2v, 0.f)
           + fmaxf(d4.y * acc2[mi][f][1] + b2v, 0.f)
           + fmaxf(d4.z * acc2[mi][f][2] + b2v, 0.f)
           + fmaxf(d4.w * acc2[mi][f][3] + b2v, 0.f);
      }
    }
    s += __shfl_xor(s, 16);
    s += __shfl_xor(s, 32);
    if (l4 == 0) pool[wv * 64 + f * 16 + l15] = s;
  }
  __syncthreads();
  if (t < 64) {
    float sum = 0.f;
#pragma unroll
    for (int w8 = 0; w8 < 8; ++w8) sum += pool[w8 * 64 + t];
    pooled[(size_t)bg * HH + q * 64 + t] = sum;
  }
}

// ---- K6: logits = (pooled/400) @ Wlin + blin. 2 graphs per block.
__global__ __launch_bounds__(256) void k_out(
    const float* __restrict__ pooled, const float* __restrict__ Wlin,
    const float* __restrict__ blin, float* __restrict__ out) {
  int bb = blockIdx.x * 2, t = threadIdx.x;
  __shared__ float ps[2][HH];
  ps[0][t] = pooled[(size_t)bb * HH + t] * (1.f / 400.f);
  ps[1][t] = pooled[(size_t)(bb + 1) * HH + t] * (1.f / 400.f);
  __syncthreads();
#pragma unroll
  for (int c = 0; c < 4; ++c) {
    int o = t + c * 256;
    if (o < OUTD) {
      float a0 = blin[o], a1 = a0;
#pragma unroll 8
      for (int h = 0; h < HH; ++h) {
        float wv = Wlin[h * OUTD + o];
        a0 += ps[0][h] * wv;
        a1 += ps[1][h] * wv;
      }
      out[(size_t)bb * OUTD + o] = a0;
      out[(size_t)(bb + 1) * OUTD + o] = a1;
    }
  }
}

extern "C" void kernel_launch(void* const* d_in, const int* in_sizes, int n_in,
                              void* d_out, int out_size, void* d_ws, size_t ws_size,
                              hipStream_t stream) {
  const float* adj   = (const float*)d_in[0];
  const float* times = (const float*)d_in[1];
  const float* W1    = (const float*)d_in[2];
  const float* b1    = (const float*)d_in[3];
  const float* W2    = (const float*)d_in[4];
  const float* b2    = (const float*)d_in[5];
  const float* Wlin  = (const float*)d_in[6];
  const float* blin  = (const float*)d_in[7];
  float* out = (float*)d_out;

  char* ws = (char*)d_ws;
  size_t off = 0;
  auto alloc = [&](size_t bytes) -> void* {
    void* ptr = ws + off;
    off = (off + bytes + 255) & ~(size_t)255;
    return ptr;
  };
  float* dis    = (float*)alloc((size_t)BATCH * NN * 4);
  float* dd     = (float*)alloc((size_t)BATCH * NN * 4);
  float* pp     = (float*)alloc((size_t)BATCH * NN * 4);
  float* qq     = (float*)alloc((size_t)BATCH * NN * 4);
  float* tproj  = (float*)alloc((size_t)BATCH * HH * 4);
  float* pooled = (float*)alloc((size_t)BATCH * HH * 4);
  short* W2Tg   = (short*)alloc((size_t)HH * W2PAD * 2);
  unsigned int* bits = (unsigned int*)alloc((size_t)BATCH * NN * BITW * 4);

  k_temb<<<BATCH, 256, 0, stream>>>(times, W1, tproj);
  k_w2t<<<HH, 256, 0, stream>>>(W2, W2Tg);
  k_prep<<<dim3(BATCH, 25), 256, 0, stream>>>(adj, bits, dis, dd);
  k_pq<<<BATCH, 512, 0, stream>>>(bits, dis, dd, pp, qq);
  k_fused<<<dim3(BATCH, 4), 512, 114688, stream>>>(
      bits, dis, pp, qq, W2Tg, W1, b1, tproj, b2, pooled);
  k_out<<<128, 256, 0, stream>>>(pooled, Wlin, blin, out);
}

// Round 13
// 158.600 us; speedup vs baseline: 1.0191x; 1.0191x over previous
//
#include <hip/hip_runtime.h>
#include <cstdint>
#include <cstddef>

#define BATCH 256
#define NN 400
#define HH 256
#define TDIM 128
#define HALFD 64
#define OUTD 800
#define BITW 16     // u32 words per bitmap row in global (13 used)
#define BMW 13
#define Y2S 416     // y2 quarter LDS row stride (shorts)

using short8  = __attribute__((ext_vector_type(8))) short;
using short4v = __attribute__((ext_vector_type(4))) short;
using f32x4   = __attribute__((ext_vector_type(4))) float;

__device__ __forceinline__ short f2bf_trunc(float x) {
  union { float f; unsigned int u; } c; c.f = x; return (short)(c.u >> 16);
}
__device__ __forceinline__ short f2bf_rne(float x) {
  union { float f; unsigned int u; } c; c.f = x;
  unsigned int r = c.u + 0x7FFFu + ((c.u >> 16) & 1u);
  return (short)(r >> 16);
}

// ---- K1: adj -> bitmap [256][400][16 u32] (binary + self loop), dis, dd.
//      (identical to the passing R6 kernel)
__global__ __launch_bounds__(256) void k_prep(const float* __restrict__ adj,
    unsigned int* __restrict__ bits, float* __restrict__ dis,
    float* __restrict__ dd) {
  int bg = blockIdx.x;
  int rbase = blockIdx.y * 16;
  int wv = threadIdx.x >> 6, lane = threadIdx.x & 63;
#pragma unroll
  for (int rr = 0; rr < 4; ++rr) {
    int i = rbase + wv * 4 + rr;
    const float* arow = adj + ((size_t)bg * NN + i) * NN;
    unsigned int b8 = 0; int c = 0;
    if (lane < 50) {
      float4 v0 = *(const float4*)(arow + 8 * lane);
      float4 v1 = *(const float4*)(arow + 8 * lane + 4);
      b8 = (v0.x != 0.f ? 1u : 0u) | (v0.y != 0.f ? 2u : 0u) |
           (v0.z != 0.f ? 4u : 0u) | (v0.w != 0.f ? 8u : 0u) |
           (v1.x != 0.f ? 16u : 0u) | (v1.y != 0.f ? 32u : 0u) |
           (v1.z != 0.f ? 64u : 0u) | (v1.w != 0.f ? 128u : 0u);
      c = __popc(b8);
      if ((i >> 3) == lane) b8 |= 1u << (i & 7);  // self loop
    }
    int cs = c;
#pragma unroll
    for (int s = 32; s; s >>= 1) cs += __shfl_xor(cs, s);
    unsigned int p0 = (unsigned int)__shfl((int)b8, 4 * lane);
    unsigned int p1 = (unsigned int)__shfl((int)b8, 4 * lane + 1);
    unsigned int p2 = (unsigned int)__shfl((int)b8, 4 * lane + 2);
    unsigned int p3 = (unsigned int)__shfl((int)b8, 4 * lane + 3);
    if (lane < BITW)
      bits[((size_t)bg * NN + i) * BITW + lane] =
          (lane < BMW) ? (p0 | (p1 << 8) | (p2 << 16) | (p3 << 24)) : 0u;
    if (lane == 0) {
      float d = rsqrtf((float)cs + 1.f);
      dis[bg * NN + i] = d;
      dd[bg * NN + i] = d * (float)cs;
    }
  }
}

// ---- K2: tproj[b,h] = temb(times[b]) @ W1[1:,:]
__global__ __launch_bounds__(256) void k_temb(
    const float* __restrict__ times, const float* __restrict__ W1,
    float* __restrict__ tproj) {
  int b = blockIdx.x, t = threadIdx.x;
  __shared__ float te[TDIM];
  if (t < HALFD) {
    float f = expf(-9.210340371976184f * (float)t / (float)(HALFD - 1));
    float arg = times[b] * f;
    te[t] = sinf(arg);
    te[t + HALFD] = cosf(arg);
  }
  __syncthreads();
  float acc = 0.f;
#pragma unroll 8
  for (int k = 0; k < TDIM; ++k) acc += te[k] * W1[(1 + k) * HH + t];
  tproj[b * HH + t] = acc;
}

// ---- K3: W2 -> bf16, MFMA-B-fragment-swizzled:
//      W2s[((q*8+k0)*4+f)*512 + lane*8 + e] = W2[k0*32+(lane>>4)*8+e][q*64+f*16+(lane&15)]
//      A wave's bf[f] load = one contiguous 1KB read (L2-resident).
__global__ __launch_bounds__(256) void k_w2s(const float* __restrict__ W2,
                                             short* __restrict__ W2s) {
  int t = threadIdx.x;
  int blk = blockIdx.x * 4 + (t >> 6);  // 0..127 = (q*8+k0)*4+f
  int lane = t & 63;
  int q = blk >> 5, k0 = (blk >> 2) & 7, f = blk & 3;
  int n = q * 64 + f * 16 + (lane & 15);
  int kb = k0 * 32 + (lane >> 4) * 8;
  short8 v;
#pragma unroll
  for (int e = 0; e < 8; ++e) v[e] = f2bf_rne(W2[(size_t)(kb + e) * HH + n]);
  *(short8*)(W2s + (size_t)blk * 512 + lane * 8) = v;
}

// ---- K4: pp = dis_i*(As@dd), qq = dis_i*(As@dis) via bitmap ctz-walk.
//      (identical to the passing R6 kernel)
__global__ __launch_bounds__(512) void k_pq(const unsigned int* __restrict__ bits,
    const float* __restrict__ dis, const float* __restrict__ dd,
    float* __restrict__ pp, float* __restrict__ qq) {
  int bg = blockIdx.x, t = threadIdx.x;
  __shared__ float sd[NN], su[NN];
  for (int j = t; j < NN; j += 512) { sd[j] = dis[bg * NN + j]; su[j] = dd[bg * NN + j]; }
  __syncthreads();
  if (t >= NN) return;
  const uint4* bp = (const uint4*)(bits + ((size_t)bg * NN + t) * BITW);
  uint4 qa = bp[0], qb = bp[1], qc = bp[2];
  unsigned int wr[13] = {qa.x, qa.y, qa.z, qa.w, qb.x, qb.y, qb.z, qb.w,
                         qc.x, qc.y, qc.z, qc.w, ((const unsigned int*)bp)[12]};
  float ps = 0.f, qs = 0.f;
#pragma unroll
  for (int w = 0; w < BMW; ++w) {
    unsigned int u = wr[w];
    int base = w * 32;
    while (u) {
      int j = base + __builtin_ctz(u);
      u &= u - 1;
      ps += su[j]; qs += sd[j];
    }
  }
  float d = sd[t];
  pp[bg * NN + t] = d * ps;
  qq[bg * NN + t] = d * qs;
}

// ---- K5: fused per-(graph, n-quarter). Identical to the PASSING R6 kernel
//      except: W2T is no longer staged in LDS (bf[f] read direct from the
//      swizzled global W2s) -> LDS 114688 -> 80896 B -> 2 blocks/CU.
__global__ __launch_bounds__(512, 2) void k_fused(
    const unsigned int* __restrict__ bits, const float* __restrict__ disg,
    const float* __restrict__ ppg, const float* __restrict__ qqg,
    const short* __restrict__ W2s, const float* __restrict__ W1,
    const float* __restrict__ b1, const float* __restrict__ tproj,
    const float* __restrict__ b2, float* __restrict__ pooled) {
  extern __shared__ char smem[];
  short* y2q         = (short*)smem;                  // 64*416*2 = 53248
  unsigned int* bmpL = (unsigned int*)(smem + 53248); // 400*13*4 = 20800 -> 74048
  float* sd          = (float*)(smem + 74048);        // 1600 -> 75648
  float* ppL         = (float*)(smem + 75648);        // 1600 -> 77248
  float* qqL         = (float*)(smem + 77248);        // 1600 -> 78848
  float* pool        = (float*)(smem + 78848);        // 2048 -> 80896 total

  int t = threadIdx.x;
  int wv = t >> 6, lane = t & 63, l15 = lane & 15, l4 = lane >> 4;
  int bg = blockIdx.x, q = blockIdx.y;

  // ---- stage: bitmap, dis/pp/qq, zero y2q pad (m=400..415)
  if (t < NN) {
    const uint4* bp = (const uint4*)(bits + ((size_t)bg * NN + t) * BITW);
    uint4 qa = bp[0], qb = bp[1], qc = bp[2];
    bmpL[t * BMW + 0] = qa.x;  bmpL[t * BMW + 1] = qa.y;
    bmpL[t * BMW + 2] = qa.z;  bmpL[t * BMW + 3] = qa.w;
    bmpL[t * BMW + 4] = qb.x;  bmpL[t * BMW + 5] = qb.y;
    bmpL[t * BMW + 6] = qb.z;  bmpL[t * BMW + 7] = qb.w;
    bmpL[t * BMW + 8] = qc.x;  bmpL[t * BMW + 9] = qc.y;
    bmpL[t * BMW + 10] = qc.z; bmpL[t * BMW + 11] = qc.w;
    bmpL[t * BMW + 12] = ((const unsigned int*)bp)[12];
    sd[t] = disg[bg * NN + t];
    ppL[t] = ppg[bg * NN + t];
    qqL[t] = qqg[bg * NN + t];
  }
  if (t < 128) {  // zero y2q pad cols m=400..415 for all 64 n-rows
    int n = t >> 1, c = t & 1;
    short8 z = {};
    *(short8*)(y2q + n * Y2S + 400 + c * 8) = z;
  }
  __syncthreads();

  // ---- GEMM1: y2q[n][m] = dis_m * (g1 @ W2)[m][q*64+n]; k0 outer, mt inner
  const float* tpr = tproj + bg * HH;
  const short* w2b = W2s + (size_t)q * 8 * 4 * 512;
  float pv[4], qv[4];
#pragma unroll
  for (int mi = 0; mi < 4; ++mi) {
    int mt = wv + mi * 8;
    int arow = mt * 16 + l15;
    pv[mi] = (mt < 25) ? ppL[arow] : 0.f;
    qv[mi] = (mt < 25) ? qqL[arow] : 0.f;
  }
  f32x4 acc[4][4];
#pragma unroll
  for (int mi = 0; mi < 4; ++mi)
#pragma unroll
    for (int f = 0; f < 4; ++f) acc[mi][f] = (f32x4){0.f, 0.f, 0.f, 0.f};

#pragma unroll
  for (int k0 = 0; k0 < 8; ++k0) {
    int kk = k0 * 32 + l4 * 8;
    float4 w1a = *(const float4*)(W1 + kk), w1b = *(const float4*)(W1 + kk + 4);
    float4 b1a = *(const float4*)(b1 + kk), b1b = *(const float4*)(b1 + kk + 4);
    float4 tpa = *(const float4*)(tpr + kk), tpb = *(const float4*)(tpr + kk + 4);
    short8 bf[4];
#pragma unroll
    for (int f = 0; f < 4; ++f)
      bf[f] = *(const short8*)(w2b + (size_t)(k0 * 4 + f) * 512 + lane * 8);
#pragma unroll
    for (int mi = 0; mi < 4; ++mi) {
      if (wv + mi * 8 < 25) {
        float ppv = pv[mi], qqv = qv[mi];
        short8 af;
        af[0] = f2bf_trunc(fmaxf(ppv * w1a.x + qqv * tpa.x + b1a.x, 0.f));
        af[1] = f2bf_trunc(fmaxf(ppv * w1a.y + qqv * tpa.y + b1a.y, 0.f));
        af[2] = f2bf_trunc(fmaxf(ppv * w1a.z + qqv * tpa.z + b1a.z, 0.f));
        af[3] = f2bf_trunc(fmaxf(ppv * w1a.w + qqv * tpa.w + b1a.w, 0.f));
        af[4] = f2bf_trunc(fmaxf(ppv * w1b.x + qqv * tpb.x + b1b.x, 0.f));
        af[5] = f2bf_trunc(fmaxf(ppv * w1b.y + qqv * tpb.y + b1b.y, 0.f));
        af[6] = f2bf_trunc(fmaxf(ppv * w1b.z + qqv * tpb.z + b1b.z, 0.f));
        af[7] = f2bf_trunc(fmaxf(ppv * w1b.w + qqv * tpb.w + b1b.w, 0.f));
#pragma unroll
        for (int f = 0; f < 4; ++f)
          acc[mi][f] = __builtin_amdgcn_mfma_f32_16x16x32_bf16(af, bf[f], acc[mi][f], 0, 0, 0);
      }
    }
  }
  // write y2q (transposed, dis-scaled): n = f*16+l15, m = mt*16 + l4*4 + r
#pragma unroll
  for (int mi = 0; mi < 4; ++mi) {
    int mt = wv + mi * 8;
    if (mt < 25) {
      float4 d4 = *(const float4*)(sd + mt * 16 + l4 * 4);
#pragma unroll
      for (int f = 0; f < 4; ++f) {
        short4v pk;
        pk[0] = f2bf_trunc(d4.x * acc[mi][f][0]);
        pk[1] = f2bf_trunc(d4.y * acc[mi][f][1]);
        pk[2] = f2bf_trunc(d4.z * acc[mi][f][2]);
        pk[3] = f2bf_trunc(d4.w * acc[mi][f][3]);
        *(short4v*)(y2q + (f * 16 + l15) * Y2S + mt * 16 + l4 * 4) = pk;
      }
    }
  }
  __syncthreads();

  // ---- AGG: C[m][n] = sum_k As[m][k]*y2q[n][k]; A-frags expanded in REGISTERS
  //      from LDS bitmap (broadcast b32 read). No LDS writes -> no barriers.
  f32x4 acc2[4][4];
#pragma unroll
  for (int mi = 0; mi < 4; ++mi)
#pragma unroll
    for (int f = 0; f < 4; ++f) acc2[mi][f] = (f32x4){0.f, 0.f, 0.f, 0.f};

#pragma unroll
  for (int ks = 0; ks < 13; ++ks) {
    short8 bfv[4];
#pragma unroll
    for (int f = 0; f < 4; ++f)
      bfv[f] = *(const short8*)(y2q + (f * 16 + l15) * Y2S + ks * 32 + l4 * 8);
#pragma unroll
    for (int mi = 0; mi < 4; ++mi) {
      int mt = wv + mi * 8;
      if (mt < 25) {
        unsigned int wd = bmpL[(mt * 16 + l15) * BMW + ks];
        unsigned int byt = (wd >> (l4 * 8)) & 0xFFu;
        short8 af;
#pragma unroll
        for (int e = 0; e < 8; ++e)
          af[e] = (short)(((byt >> e) & 1u) * 0x3F80u);
#pragma unroll
        for (int f = 0; f < 4; ++f)
          acc2[mi][f] = __builtin_amdgcn_mfma_f32_16x16x32_bf16(af, bfv[f], acc2[mi][f], 0, 0, 0);
      }
    }
  }

  // ---- epilogue: s(n) = sum_m relu(dis_m * C[m][n] + b2[n]); pool across waves
#pragma unroll
  for (int f = 0; f < 4; ++f) {
    float b2v = b2[q * 64 + f * 16 + l15];
    float s = 0.f;
#pragma unroll
    for (int mi = 0; mi < 4; ++mi) {
      int mt = wv + mi * 8;
      if (mt < 25) {
        float4 d4 = *(const float4*)(sd + mt * 16 + l4 * 4);
        s += fmaxf(d4.x * acc2[mi][f][0] + b2v, 0.f)
           + fmaxf(d4.y * acc2[mi][f][1] + b2v, 0.f)
           + fmaxf(d4.z * acc2[mi][f][2] + b2v, 0.f)
           + fmaxf(d4.w * acc2[mi][f][3] + b2v, 0.f);
      }
    }
    s += __shfl_xor(s, 16);
    s += __shfl_xor(s, 32);
    if (l4 == 0) pool[wv * 64 + f * 16 + l15] = s;
  }
  __syncthreads();
  if (t < 64) {
    float sum = 0.f;
#pragma unroll
    for (int w8 = 0; w8 < 8; ++w8) sum += pool[w8 * 64 + t];
    pooled[(size_t)bg * HH + q * 64 + t] = sum;
  }
}

// ---- K6: logits = (pooled/400) @ Wlin + blin. 2 graphs per block.
__global__ __launch_bounds__(256) void k_out(
    const float* __restrict__ pooled, const float* __restrict__ Wlin,
    const float* __restrict__ blin, float* __restrict__ out) {
  int bb = blockIdx.x * 2, t = threadIdx.x;
  __shared__ float ps[2][HH];
  ps[0][t] = pooled[(size_t)bb * HH + t] * (1.f / 400.f);
  ps[1][t] = pooled[(size_t)(bb + 1) * HH + t] * (1.f / 400.f);
  __syncthreads();
#pragma unroll
  for (int c = 0; c < 4; ++c) {
    int o = t + c * 256;
    if (o < OUTD) {
      float a0 = blin[o], a1 = a0;
#pragma unroll 8
      for (int h = 0; h < HH; ++h) {
        float wv = Wlin[h * OUTD + o];
        a0 += ps[0][h] * wv;
        a1 += ps[1][h] * wv;
      }
      out[(size_t)bb * OUTD + o] = a0;
      out[(size_t)(bb + 1) * OUTD + o] = a1;
    }
  }
}

extern "C" void kernel_launch(void* const* d_in, const int* in_sizes, int n_in,
                              void* d_out, int out_size, void* d_ws, size_t ws_size,
                              hipStream_t stream) {
  const float* adj   = (const float*)d_in[0];
  const float* times = (const float*)d_in[1];
  const float* W1    = (const float*)d_in[2];
  const float* b1    = (const float*)d_in[3];
  const float* W2    = (const float*)d_in[4];
  const float* b2    = (const float*)d_in[5];
  const float* Wlin  = (const float*)d_in[6];
  const float* blin  = (const float*)d_in[7];
  float* out = (float*)d_out;

  char* ws = (char*)d_ws;
  size_t off = 0;
  auto alloc = [&](size_t bytes) -> void* {
    void* ptr = ws + off;
    off = (off + bytes + 255) & ~(size_t)255;
    return ptr;
  };
  float* dis    = (float*)alloc((size_t)BATCH * NN * 4);
  float* dd     = (float*)alloc((size_t)BATCH * NN * 4);
  float* pp     = (float*)alloc((size_t)BATCH * NN * 4);
  float* qq     = (float*)alloc((size_t)BATCH * NN * 4);
  float* tproj  = (float*)alloc((size_t)BATCH * HH * 4);
  float* pooled = (float*)alloc((size_t)BATCH * HH * 4);
  short* W2s    = (short*)alloc((size_t)128 * 512 * 2);
  unsigned int* bits = (unsigned int*)alloc((size_t)BATCH * NN * BITW * 4);

  k_temb<<<BATCH, 256, 0, stream>>>(times, W1, tproj);
  k_w2s<<<32, 256, 0, stream>>>(W2, W2s);
  k_prep<<<dim3(BATCH, 25), 256, 0, stream>>>(adj, bits, dis, dd);
  k_pq<<<BATCH, 512, 0, stream>>>(bits, dis, dd, pp, qq);
  k_fused<<<dim3(BATCH, 4), 512, 80896, stream>>>(
      bits, dis, pp, qq, W2s, W1, b1, tproj, b2, pooled);
  k_out<<<128, 256, 0, stream>>>(pooled, Wlin, blin, out);
}

// Round 14
// 150.255 us; speedup vs baseline: 1.0757x; 1.0555x over previous
//
#include <hip/hip_runtime.h>
#include <cstdint>
#include <cstddef>

#define BATCH 256
#define NN 400
#define HH 256
#define TDIM 128
#define HALFD 64
#define OUTD 800
#define BITW 16     // u32 words per bitmap row in global (13 used)
#define BMW 13
#define Y2S 424     // y2 LDS row stride (shorts): dword-stride 212 = 4*53 -> 2-way banks (free)

using short8  = __attribute__((ext_vector_type(8))) short;
using short4v = __attribute__((ext_vector_type(4))) short;
using f32x4   = __attribute__((ext_vector_type(4))) float;

__device__ __forceinline__ short f2bf_trunc(float x) {
  union { float f; unsigned int u; } c; c.f = x; return (short)(c.u >> 16);
}
__device__ __forceinline__ short f2bf_rne(float x) {
  union { float f; unsigned int u; } c; c.f = x;
  unsigned int r = c.u + 0x7FFFu + ((c.u >> 16) & 1u);
  return (short)(r >> 16);
}

// ---- K1: adj -> bitmap [256][400][16 u32] (binary + self loop), dis, dd.
//      (unchanged, passing since R6)
__global__ __launch_bounds__(256) void k_prep(const float* __restrict__ adj,
    unsigned int* __restrict__ bits, float* __restrict__ dis,
    float* __restrict__ dd) {
  int bg = blockIdx.x;
  int rbase = blockIdx.y * 16;
  int wv = threadIdx.x >> 6, lane = threadIdx.x & 63;
#pragma unroll
  for (int rr = 0; rr < 4; ++rr) {
    int i = rbase + wv * 4 + rr;
    const float* arow = adj + ((size_t)bg * NN + i) * NN;
    unsigned int b8 = 0; int c = 0;
    if (lane < 50) {
      float4 v0 = *(const float4*)(arow + 8 * lane);
      float4 v1 = *(const float4*)(arow + 8 * lane + 4);
      b8 = (v0.x != 0.f ? 1u : 0u) | (v0.y != 0.f ? 2u : 0u) |
           (v0.z != 0.f ? 4u : 0u) | (v0.w != 0.f ? 8u : 0u) |
           (v1.x != 0.f ? 16u : 0u) | (v1.y != 0.f ? 32u : 0u) |
           (v1.z != 0.f ? 64u : 0u) | (v1.w != 0.f ? 128u : 0u);
      c = __popc(b8);
      if ((i >> 3) == lane) b8 |= 1u << (i & 7);  // self loop
    }
    int cs = c;
#pragma unroll
    for (int s = 32; s; s >>= 1) cs += __shfl_xor(cs, s);
    unsigned int p0 = (unsigned int)__shfl((int)b8, 4 * lane);
    unsigned int p1 = (unsigned int)__shfl((int)b8, 4 * lane + 1);
    unsigned int p2 = (unsigned int)__shfl((int)b8, 4 * lane + 2);
    unsigned int p3 = (unsigned int)__shfl((int)b8, 4 * lane + 3);
    if (lane < BITW)
      bits[((size_t)bg * NN + i) * BITW + lane] =
          (lane < BMW) ? (p0 | (p1 << 8) | (p2 << 16) | (p3 << 24)) : 0u;
    if (lane == 0) {
      float d = rsqrtf((float)cs + 1.f);
      dis[bg * NN + i] = d;
      dd[bg * NN + i] = d * (float)cs;
    }
  }
}

// ---- K2: tproj[b,h] = temb(times[b]) @ W1[1:,:]  (unchanged)
__global__ __launch_bounds__(256) void k_temb(
    const float* __restrict__ times, const float* __restrict__ W1,
    float* __restrict__ tproj) {
  int b = blockIdx.x, t = threadIdx.x;
  __shared__ float te[TDIM];
  if (t < HALFD) {
    float f = expf(-9.210340371976184f * (float)t / (float)(HALFD - 1));
    float arg = times[b] * f;
    te[t] = sinf(arg);
    te[t + HALFD] = cosf(arg);
  }
  __syncthreads();
  float acc = 0.f;
#pragma unroll 8
  for (int k = 0; k < TDIM; ++k) acc += te[k] * W1[(1 + k) * HH + t];
  tproj[b * HH + t] = acc;
}

// ---- K3: W2 -> bf16, MFMA-B-fragment-swizzled (unchanged)
__global__ __launch_bounds__(256) void k_w2s(const float* __restrict__ W2,
                                             short* __restrict__ W2s) {
  int t = threadIdx.x;
  int blk = blockIdx.x * 4 + (t >> 6);  // 0..127 = (q*8+k0)*4+f
  int lane = t & 63;
  int q = blk >> 5, k0 = (blk >> 2) & 7, f = blk & 3;
  int n = q * 64 + f * 16 + (lane & 15);
  int kb = k0 * 32 + (lane >> 4) * 8;
  short8 v;
#pragma unroll
  for (int e = 0; e < 8; ++e) v[e] = f2bf_rne(W2[(size_t)(kb + e) * HH + n]);
  *(short8*)(W2s + (size_t)blk * 512 + lane * 8) = v;
}

// ---- K4: pp/qq via bitmap ctz-walk (unchanged)
__global__ __launch_bounds__(512) void k_pq(const unsigned int* __restrict__ bits,
    const float* __restrict__ dis, const float* __restrict__ dd,
    float* __restrict__ pp, float* __restrict__ qq) {
  int bg = blockIdx.x, t = threadIdx.x;
  __shared__ float sd[NN], su[NN];
  for (int j = t; j < NN; j += 512) { sd[j] = dis[bg * NN + j]; su[j] = dd[bg * NN + j]; }
  __syncthreads();
  if (t >= NN) return;
  const uint4* bp = (const uint4*)(bits + ((size_t)bg * NN + t) * BITW);
  uint4 qa = bp[0], qb = bp[1], qc = bp[2];
  unsigned int wr[13] = {qa.x, qa.y, qa.z, qa.w, qb.x, qb.y, qb.z, qb.w,
                         qc.x, qc.y, qc.z, qc.w, ((const unsigned int*)bp)[12]};
  float ps = 0.f, qs = 0.f;
#pragma unroll
  for (int w = 0; w < BMW; ++w) {
    unsigned int u = wr[w];
    int base = w * 32;
    while (u) {
      int j = base + __builtin_ctz(u);
      u &= u - 1;
      ps += su[j]; qs += sd[j];
    }
  }
  float d = sd[t];
  pp[bg * NN + t] = d * ps;
  qq[bg * NN + t] = d * qs;
}

// ---- K5: fused per-(graph, n-quarter). R13 body + (a) nibble-LUT af expansion
//      (moves AGG bit-expand from 30 VALU to 2 LDS b64 reads), (b) Y2S 424
//      (conflict-free y2q), (c) pool aliased onto dead ppL/qqL. LDS = 80000 B.
__global__ __launch_bounds__(512, 2) void k_fused(
    const unsigned int* __restrict__ bits, const float* __restrict__ disg,
    const float* __restrict__ ppg, const float* __restrict__ qqg,
    const short* __restrict__ W2s, const float* __restrict__ W1,
    const float* __restrict__ b1, const float* __restrict__ tproj,
    const float* __restrict__ b2, float* __restrict__ pooled) {
  extern __shared__ char smem[];
  short* y2q         = (short*)smem;                  // 64*424*2 = 54272
  unsigned int* bmpL = (unsigned int*)(smem + 54272); // 400*13*4 = 20800 -> 75072
  float* sd          = (float*)(smem + 75072);        // 1600 -> 76672
  float* ppL         = (float*)(smem + 76672);        // 1600 -> 78272
  float* qqL         = (float*)(smem + 78272);        // 1600 -> 79872
  short* lut4        = (short*)(smem + 79872);        // 16*4*2 = 128 -> 80000 total
  float* pool        = (float*)(smem + 76672);        // alias ppL+qqL (dead after GEMM1)

  int t = threadIdx.x;
  int wv = t >> 6, lane = t & 63, l15 = lane & 15, l4 = lane >> 4;
  int bg = blockIdx.x, q = blockIdx.y;

  // ---- stage: bitmap, dis/pp/qq, LUT, zero y2q pad (m=400..423)
  if (t < NN) {
    const uint4* bp = (const uint4*)(bits + ((size_t)bg * NN + t) * BITW);
    uint4 qa = bp[0], qb = bp[1], qc = bp[2];
    bmpL[t * BMW + 0] = qa.x;  bmpL[t * BMW + 1] = qa.y;
    bmpL[t * BMW + 2] = qa.z;  bmpL[t * BMW + 3] = qa.w;
    bmpL[t * BMW + 4] = qb.x;  bmpL[t * BMW + 5] = qb.y;
    bmpL[t * BMW + 6] = qb.z;  bmpL[t * BMW + 7] = qb.w;
    bmpL[t * BMW + 8] = qc.x;  bmpL[t * BMW + 9] = qc.y;
    bmpL[t * BMW + 10] = qc.z; bmpL[t * BMW + 11] = qc.w;
    bmpL[t * BMW + 12] = ((const unsigned int*)bp)[12];
    sd[t] = disg[bg * NN + t];
    ppL[t] = ppg[bg * NN + t];
    qqL[t] = qqg[bg * NN + t];
  }
  if (t < 192) {  // zero y2q pad cols m=400..423 for all 64 n-rows
    int n = t / 3, c = t % 3;
    short8 z = {};
    *(short8*)(y2q + n * Y2S + 400 + c * 8) = z;
  }
  if (t < 16) {   // nibble LUT: lut4[n][e] = bit e of n as bf16 1.0/0.0
    short4v v;
#pragma unroll
    for (int e = 0; e < 4; ++e) v[e] = ((t >> e) & 1) ? (short)0x3F80 : (short)0;
    *(short4v*)(lut4 + t * 4) = v;
  }
  __syncthreads();

  // ---- GEMM1: y2q[n][m] = dis_m * (g1 @ W2)[m][q*64+n]; k0 outer, mt inner
  const float* tpr = tproj + bg * HH;
  const short* w2b = W2s + (size_t)q * 8 * 4 * 512;
  float pv[4], qv[4];
#pragma unroll
  for (int mi = 0; mi < 4; ++mi) {
    int mt = wv + mi * 8;
    int arow = mt * 16 + l15;
    pv[mi] = (mt < 25) ? ppL[arow] : 0.f;
    qv[mi] = (mt < 25) ? qqL[arow] : 0.f;
  }
  f32x4 acc[4][4];
#pragma unroll
  for (int mi = 0; mi < 4; ++mi)
#pragma unroll
    for (int f = 0; f < 4; ++f) acc[mi][f] = (f32x4){0.f, 0.f, 0.f, 0.f};

#pragma unroll
  for (int k0 = 0; k0 < 8; ++k0) {
    int kk = k0 * 32 + l4 * 8;
    float4 w1a = *(const float4*)(W1 + kk), w1b = *(const float4*)(W1 + kk + 4);
    float4 b1a = *(const float4*)(b1 + kk), b1b = *(const float4*)(b1 + kk + 4);
    float4 tpa = *(const float4*)(tpr + kk), tpb = *(const float4*)(tpr + kk + 4);
    short8 bf[4];
#pragma unroll
    for (int f = 0; f < 4; ++f)
      bf[f] = *(const short8*)(w2b + (size_t)(k0 * 4 + f) * 512 + lane * 8);
#pragma unroll
    for (int mi = 0; mi < 4; ++mi) {
      if (wv + mi * 8 < 25) {
        float ppv = pv[mi], qqv = qv[mi];
        short8 af;
        af[0] = f2bf_trunc(fmaxf(ppv * w1a.x + qqv * tpa.x + b1a.x, 0.f));
        af[1] = f2bf_trunc(fmaxf(ppv * w1a.y + qqv * tpa.y + b1a.y, 0.f));
        af[2] = f2bf_trunc(fmaxf(ppv * w1a.z + qqv * tpa.z + b1a.z, 0.f));
        af[3] = f2bf_trunc(fmaxf(ppv * w1a.w + qqv * tpa.w + b1a.w, 0.f));
        af[4] = f2bf_trunc(fmaxf(ppv * w1b.x + qqv * tpb.x + b1b.x, 0.f));
        af[5] = f2bf_trunc(fmaxf(ppv * w1b.y + qqv * tpb.y + b1b.y, 0.f));
        af[6] = f2bf_trunc(fmaxf(ppv * w1b.z + qqv * tpb.z + b1b.z, 0.f));
        af[7] = f2bf_trunc(fmaxf(ppv * w1b.w + qqv * tpb.w + b1b.w, 0.f));
#pragma unroll
        for (int f = 0; f < 4; ++f)
          acc[mi][f] = __builtin_amdgcn_mfma_f32_16x16x32_bf16(af, bf[f], acc[mi][f], 0, 0, 0);
      }
    }
  }
  // write y2q (transposed, dis-scaled): n = f*16+l15, m = mt*16 + l4*4 + r
#pragma unroll
  for (int mi = 0; mi < 4; ++mi) {
    int mt = wv + mi * 8;
    if (mt < 25) {
      float4 d4 = *(const float4*)(sd + mt * 16 + l4 * 4);
#pragma unroll
      for (int f = 0; f < 4; ++f) {
        short4v pk;
        pk[0] = f2bf_trunc(d4.x * acc[mi][f][0]);
        pk[1] = f2bf_trunc(d4.y * acc[mi][f][1]);
        pk[2] = f2bf_trunc(d4.z * acc[mi][f][2]);
        pk[3] = f2bf_trunc(d4.w * acc[mi][f][3]);
        *(short4v*)(y2q + (f * 16 + l15) * Y2S + mt * 16 + l4 * 4) = pk;
      }
    }
  }
  __syncthreads();

  // ---- AGG: C[m][n] = sum_k As[m][k]*y2q[n][k]; A-frags via nibble LUT
  //      (2 ds_read_b64 per frag instead of ~30 VALU). Read-only LDS, no barriers.
  f32x4 acc2[4][4];
#pragma unroll
  for (int mi = 0; mi < 4; ++mi)
#pragma unroll
    for (int f = 0; f < 4; ++f) acc2[mi][f] = (f32x4){0.f, 0.f, 0.f, 0.f};

#pragma unroll
  for (int ks = 0; ks < 13; ++ks) {
    short8 bfv[4];
#pragma unroll
    for (int f = 0; f < 4; ++f)
      bfv[f] = *(const short8*)(y2q + (f * 16 + l15) * Y2S + ks * 32 + l4 * 8);
#pragma unroll
    for (int mi = 0; mi < 4; ++mi) {
      int mt = wv + mi * 8;
      if (mt < 25) {
        unsigned int wd = bmpL[(mt * 16 + l15) * BMW + ks];
        unsigned int byt = (wd >> (l4 * 8)) & 0xFFu;
        short4v lo = *(const short4v*)(lut4 + (byt & 15u) * 4);
        short4v hi = *(const short4v*)(lut4 + (byt >> 4) * 4);
        short8 af;
        af[0] = lo[0]; af[1] = lo[1]; af[2] = lo[2]; af[3] = lo[3];
        af[4] = hi[0]; af[5] = hi[1]; af[6] = hi[2]; af[7] = hi[3];
#pragma unroll
        for (int f = 0; f < 4; ++f)
          acc2[mi][f] = __builtin_amdgcn_mfma_f32_16x16x32_bf16(af, bfv[f], acc2[mi][f], 0, 0, 0);
      }
    }
  }

  // ---- epilogue: s(n) = sum_m relu(dis_m * C[m][n] + b2[n]); pool across waves
#pragma unroll
  for (int f = 0; f < 4; ++f) {
    float b2v = b2[q * 64 + f * 16 + l15];
    float s = 0.f;
#pragma unroll
    for (int mi = 0; mi < 4; ++mi) {
      int mt = wv + mi * 8;
      if (mt < 25) {
        float4 d4 = *(const float4*)(sd + mt * 16 + l4 * 4);
        s += fmaxf(d4.x * acc2[mi][f][0] + b2v, 0.f)
           + fmaxf(d4.y * acc2[mi][f][1] + b2v, 0.f)
           + fmaxf(d4.z * acc2[mi][f][2] + b2v, 0.f)
           + fmaxf(d4.w * acc2[mi][f][3] + b2v, 0.f);
      }
    }
    s += __shfl_xor(s, 16);
    s += __shfl_xor(s, 32);
    if (l4 == 0) pool[wv * 64 + f * 16 + l15] = s;  // pool aliases dead ppL/qqL
  }
  __syncthreads();
  if (t < 64) {
    float sum = 0.f;
#pragma unroll
    for (int w8 = 0; w8 < 8; ++w8) sum += pool[w8 * 64 + t];
    pooled[(size_t)bg * HH + q * 64 + t] = sum;
  }
}

// ---- K6: logits = (pooled/400) @ Wlin + blin. 2 graphs per block. (unchanged)
__global__ __launch_bounds__(256) void k_out(
    const float* __restrict__ pooled, const float* __restrict__ Wlin,
    const float* __restrict__ blin, float* __restrict__ out) {
  int bb = blockIdx.x * 2, t = threadIdx.x;
  __shared__ float ps[2][HH];
  ps[0][t] = pooled[(size_t)bb * HH + t] * (1.f / 400.f);
  ps[1][t] = pooled[(size_t)(bb + 1) * HH + t] * (1.f / 400.f);
  __syncthreads();
#pragma unroll
  for (int c = 0; c < 4; ++c) {
    int o = t + c * 256;
    if (o < OUTD) {
      float a0 = blin[o], a1 = a0;
#pragma unroll 8
      for (int h = 0; h < HH; ++h) {
        float wv = Wlin[h * OUTD + o];
        a0 += ps[0][h] * wv;
        a1 += ps[1][h] * wv;
      }
      out[(size_t)bb * OUTD + o] = a0;
      out[(size_t)(bb + 1) * OUTD + o] = a1;
    }
  }
}

extern "C" void kernel_launch(void* const* d_in, const int* in_sizes, int n_in,
                              void* d_out, int out_size, void* d_ws, size_t ws_size,
                              hipStream_t stream) {
  const float* adj   = (const float*)d_in[0];
  const float* times = (const float*)d_in[1];
  const float* W1    = (const float*)d_in[2];
  const float* b1    = (const float*)d_in[3];
  const float* W2    = (const float*)d_in[4];
  const float* b2    = (const float*)d_in[5];
  const float* Wlin  = (const float*)d_in[6];
  const float* blin  = (const float*)d_in[7];
  float* out = (float*)d_out;

  char* ws = (char*)d_ws;
  size_t off = 0;
  auto alloc = [&](size_t bytes) -> void* {
    void* ptr = ws + off;
    off = (off + bytes + 255) & ~(size_t)255;
    return ptr;
  };
  float* dis    = (float*)alloc((size_t)BATCH * NN * 4);
  float* dd     = (float*)alloc((size_t)BATCH * NN * 4);
  float* pp     = (float*)alloc((size_t)BATCH * NN * 4);
  float* qq     = (float*)alloc((size_t)BATCH * NN * 4);
  float* tproj  = (float*)alloc((size_t)BATCH * HH * 4);
  float* pooled = (float*)alloc((size_t)BATCH * HH * 4);
  short* W2s    = (short*)alloc((size_t)128 * 512 * 2);
  unsigned int* bits = (unsigned int*)alloc((size_t)BATCH * NN * BITW * 4);

  k_temb<<<BATCH, 256, 0, stream>>>(times, W1, tproj);
  k_w2s<<<32, 256, 0, stream>>>(W2, W2s);
  k_prep<<<dim3(BATCH, 25), 256, 0, stream>>>(adj, bits, dis, dd);
  k_pq<<<BATCH, 512, 0, stream>>>(bits, dis, dd, pp, qq);
  k_fused<<<dim3(BATCH, 4), 512, 80000, stream>>>(
      bits, dis, pp, qq, W2s, W1, b1, tproj, b2, pooled);
  k_out<<<128, 256, 0, stream>>>(pooled, Wlin, blin, out);
}